// Round 1
// baseline (128.494 us; speedup 1.0000x reference)
//
#include <hip/hip_runtime.h>

// NT-Xent (SimCLR) loss, B=2048, D=256, N=4096, T=0.5, eps=1e-8.
// sim values are cosine/T in [-2,2] -> exp never overflows -> no online max.
// Plan: (1) normalize rows -> bf16 zn in ws; (2) MFMA bf16 GEMM tiles fused
// with exp-sum (diag excluded) + positive-pair capture; (3) tiny reduction.

#define NROWS 4096
#define DDIM 256
#define BHALF 2048
#define NSPLIT 16   // column splits in kernel 2
#define INV_T 2.0f

typedef short bf16x8 __attribute__((ext_vector_type(8)));
typedef float f32x4 __attribute__((ext_vector_type(4)));

__device__ inline unsigned short f2bf(float f) {
    union { float f; unsigned u; } c; c.f = f;
    unsigned u = c.u + 0x7fffu + ((c.u >> 16) & 1u);  // RNE
    return (unsigned short)(u >> 16);
}

// ---- Kernel 1: row-normalize z=[z_i;z_j] into bf16 zn[4096][256] ----------
__global__ __launch_bounds__(256) void k_normalize(
    const float* __restrict__ zi, const float* __restrict__ zj,
    unsigned short* __restrict__ zn) {
    const int wave = threadIdx.x >> 6, lane = threadIdx.x & 63;
    const int row = blockIdx.x * 4 + wave;           // grid = 1024 blocks
    const float* src = (row < BHALF) ? (zi + row * DDIM)
                                     : (zj + (row - BHALF) * DDIM);
    const float4 v = ((const float4*)src)[lane];     // 4 floats/lane
    float ss = v.x * v.x + v.y * v.y + v.z * v.z + v.w * v.w;
    #pragma unroll
    for (int m = 1; m < 64; m <<= 1) ss += __shfl_xor(ss, m);
    const float scale = 1.0f / fmaxf(sqrtf(ss), 1e-8f);
    ushort4 o;
    o.x = f2bf(v.x * scale); o.y = f2bf(v.y * scale);
    o.z = f2bf(v.z * scale); o.w = f2bf(v.w * scale);
    ((ushort4*)(zn + row * DDIM))[lane] = o;
}

// ---- Kernel 2: fused sim-GEMM + exp-sum (excl. diag) + positive capture ---
// grid = (64 row tiles, NSPLIT col splits); block = 256 threads = 4 waves.
// Wave w owns rows [bx*64 + w*16, +16); sweeps 4096/NSPLIT columns in 16-col
// chunks via mfma_f32_16x16x32_bf16 (K-loop of 8 over D=256).
__global__ __launch_bounds__(256) void k_simlse(
    const unsigned short* __restrict__ zn,
    float* __restrict__ partial,     // [NSPLIT][4096]
    float* __restrict__ posv) {      // [4096]
    const int wave = threadIdx.x >> 6, lane = threadIdx.x & 63;
    const int quad = lane >> 4, l15 = lane & 15;
    const int rowBase = blockIdx.x * 64 + wave * 16;
    const int colBase0 = blockIdx.y * (NROWS / NSPLIT);

    // Preload A fragments for this wave's 16 rows, all 8 K-steps.
    // A[m=lane&15][k = ks*32 + quad*8 + j], j in [0,8): 16B contiguous.
    const int growA = rowBase + l15;
    const bf16x8* aptr = (const bf16x8*)(zn + growA * DDIM + quad * 8);
    bf16x8 afrag[8];
    #pragma unroll
    for (int ks = 0; ks < 8; ++ks) afrag[ks] = aptr[ks * 4];  // 32 shorts apart

    float sum[4] = {0.f, 0.f, 0.f, 0.f};

    for (int ct = 0; ct < (NROWS / NSPLIT) / 16; ++ct) {
        const int gcol = colBase0 + ct * 16 + l15;
        // B[k][n]: n = lane&15 (sim column = zn row gcol), k = ks*32+quad*8+j
        const bf16x8* bptr = (const bf16x8*)(zn + gcol * DDIM + quad * 8);
        bf16x8 bfrag[8];
        #pragma unroll
        for (int ks = 0; ks < 8; ++ks) bfrag[ks] = bptr[ks * 4];

        f32x4 acc = {0.f, 0.f, 0.f, 0.f};
        #pragma unroll
        for (int ks = 0; ks < 8; ++ks)
            acc = __builtin_amdgcn_mfma_f32_16x16x32_bf16(
                afrag[ks], bfrag[ks], acc, 0, 0, 0);

        // C/D: col = lane&15, row = quad*4 + r   [verified layout]
        #pragma unroll
        for (int r = 0; r < 4; ++r) {
            const int grow = rowBase + quad * 4 + r;
            const float simv = acc[r] * INV_T;
            if (gcol != grow) sum[r] += __expf(simv);    // exclude diagonal
            if (gcol == grow + BHALF || grow == gcol + BHALF)
                posv[grow] = simv;                        // unique writer
        }
    }

    // Reduce partial sums across the 16 column-lanes of each quad.
    #pragma unroll
    for (int r = 0; r < 4; ++r) {
        float v = sum[r];
        v += __shfl_xor(v, 1); v += __shfl_xor(v, 2);
        v += __shfl_xor(v, 4); v += __shfl_xor(v, 8);
        if (l15 == 0)
            partial[blockIdx.y * NROWS + rowBase + quad * 4 + r] = v;
    }
}

// ---- Kernel 3: loss = mean_i( log(sum_exp_i) - pos_i ) --------------------
__global__ __launch_bounds__(256) void k_finalize(
    const float* __restrict__ partial, const float* __restrict__ posv,
    float* __restrict__ out) {
    __shared__ float red[4];
    const int tid = threadIdx.x;
    float acc = 0.f;
    for (int i = tid; i < NROWS; i += 256) {
        float s = 0.f;
        #pragma unroll
        for (int p = 0; p < NSPLIT; ++p) s += partial[p * NROWS + i];
        acc += __logf(s) - posv[i];
    }
    #pragma unroll
    for (int m = 1; m < 64; m <<= 1) acc += __shfl_xor(acc, m);
    if ((tid & 63) == 0) red[tid >> 6] = acc;
    __syncthreads();
    if (tid == 0)
        out[0] = (red[0] + red[1] + red[2] + red[3]) * (1.0f / (float)NROWS);
}

extern "C" void kernel_launch(void* const* d_in, const int* in_sizes, int n_in,
                              void* d_out, int out_size, void* d_ws, size_t ws_size,
                              hipStream_t stream) {
    const float* zi = (const float*)d_in[0];
    const float* zj = (const float*)d_in[1];
    float* out = (float*)d_out;

    unsigned short* zn = (unsigned short*)d_ws;                 // 2 MB
    float* partial = (float*)((char*)d_ws + NROWS * DDIM * 2);  // 256 KB
    float* posv = partial + NSPLIT * NROWS;                     // 16 KB

    k_normalize<<<NROWS / 4, 256, 0, stream>>>(zi, zj, zn);
    k_simlse<<<dim3(NROWS / 64, NSPLIT), 256, 0, stream>>>(zn, partial, posv);
    k_finalize<<<1, 256, 0, stream>>>(partial, posv, out);
}

// Round 2
// 82.111 us; speedup vs baseline: 1.5649x; 1.5649x over previous
//
#include <hip/hip_runtime.h>

// NT-Xent (SimCLR) loss, B=2048, D=256, N=4096, T=0.5, eps=1e-8.
// R2: LDS-staged 128x128 MFMA tiles (scattered per-lane B-gathers in R1 left
// all pipes <10% busy — L1 miss-path serialization). Multi-block finalize.

#define NROWS 4096
#define DDIM 256
#define BHALF 2048
#define TILE 128
#define BK 64
#define LDP 72      // padded LDS row stride in shorts: 144B = 9*16B (aligned, 2-way banks)
#define NCB (NROWS / TILE)   // 32 col-blocks
#define INV_T 2.0f

typedef short bf16x8 __attribute__((ext_vector_type(8)));
typedef float f32x4 __attribute__((ext_vector_type(4)));

__device__ inline unsigned short f2bf(float f) {
    union { float f; unsigned u; } c; c.f = f;
    unsigned u = c.u + 0x7fffu + ((c.u >> 16) & 1u);  // RNE
    return (unsigned short)(u >> 16);
}

// ---- Kernel 1: row-normalize z=[z_i;z_j] into bf16 zn[4096][256] ----------
__global__ __launch_bounds__(256) void k_normalize(
    const float* __restrict__ zi, const float* __restrict__ zj,
    unsigned short* __restrict__ zn) {
    const int wave = threadIdx.x >> 6, lane = threadIdx.x & 63;
    const int row = blockIdx.x * 4 + wave;
    const float* src = (row < BHALF) ? (zi + row * DDIM)
                                     : (zj + (row - BHALF) * DDIM);
    const float4 v = ((const float4*)src)[lane];
    float ss = v.x * v.x + v.y * v.y + v.z * v.z + v.w * v.w;
    #pragma unroll
    for (int m = 1; m < 64; m <<= 1) ss += __shfl_xor(ss, m);
    const float scale = 1.0f / fmaxf(sqrtf(ss), 1e-8f);
    ushort4 o;
    o.x = f2bf(v.x * scale); o.y = f2bf(v.y * scale);
    o.z = f2bf(v.z * scale); o.w = f2bf(v.w * scale);
    ((ushort4*)(zn + row * DDIM))[lane] = o;
}

// ---- Kernel 2: LDS-tiled sim GEMM fused with exp-sum + positive capture ---
// grid (32,32); block 256 = 4 waves in 2x2; each wave computes 64x64 via
// 4x4 mfma_f32_16x16x32_bf16. A/B tiles (128x64 bf16) staged in padded LDS.
__global__ __launch_bounds__(256) void k_simlse(
    const unsigned short* __restrict__ zn,
    float* __restrict__ partial,     // [NCB][4096]
    float* __restrict__ posv) {      // [4096]
    __shared__ unsigned short As[TILE * LDP];
    __shared__ unsigned short Bs[TILE * LDP];
    __shared__ float pscratch[TILE];

    const int tid = threadIdx.x;
    const int wave = tid >> 6, lane = tid & 63;
    const int quad = lane >> 4, l15 = lane & 15;
    const int wr = wave >> 1, wc = wave & 1;       // 2x2 wave grid
    const int rowBase = blockIdx.x * TILE;
    const int colBase = blockIdx.y * TILE;

    f32x4 acc[4][4] = {};

    for (int kb = 0; kb < DDIM / BK; ++kb) {
        __syncthreads();   // previous compute done before LDS overwrite
        #pragma unroll
        for (int i = 0; i < 4; ++i) {
            const int flat = tid + i * 256;        // 0..1023
            const int r = flat >> 3, c = flat & 7; // row, 8-short chunk
            *(bf16x8*)&As[r * LDP + c * 8] =
                *(const bf16x8*)&zn[(rowBase + r) * DDIM + kb * BK + c * 8];
            *(bf16x8*)&Bs[r * LDP + c * 8] =
                *(const bf16x8*)&zn[(colBase + r) * DDIM + kb * BK + c * 8];
        }
        __syncthreads();
        #pragma unroll
        for (int s = 0; s < 2; ++s) {              // two K=32 sub-steps
            bf16x8 af[4], bf[4];
            #pragma unroll
            for (int mt = 0; mt < 4; ++mt)
                af[mt] = *(const bf16x8*)&As[(wr * 64 + mt * 16 + l15) * LDP + s * 32 + quad * 8];
            #pragma unroll
            for (int nt = 0; nt < 4; ++nt)
                bf[nt] = *(const bf16x8*)&Bs[(wc * 64 + nt * 16 + l15) * LDP + s * 32 + quad * 8];
            #pragma unroll
            for (int mt = 0; mt < 4; ++mt)
                #pragma unroll
                for (int nt = 0; nt < 4; ++nt)
                    acc[mt][nt] = __builtin_amdgcn_mfma_f32_16x16x32_bf16(
                        af[mt], bf[nt], acc[mt][nt], 0, 0, 0);
        }
    }

    // Epilogue: scale, exclude diag, capture positive, per-row exp-sums.
    // C/D layout: col = lane&15, row = quad*4 + r.
    float ssum[4][4];   // [mt][r], all lanes hold the row total after butterfly
    #pragma unroll
    for (int mt = 0; mt < 4; ++mt) {
        #pragma unroll
        for (int r = 0; r < 4; ++r) {
            const int grow = rowBase + wr * 64 + mt * 16 + quad * 4 + r;
            float s = 0.f;
            #pragma unroll
            for (int nt = 0; nt < 4; ++nt) {
                const int gcol = colBase + wc * 64 + nt * 16 + l15;
                const float simv = acc[mt][nt][r] * INV_T;
                if (gcol != grow) s += __expf(simv);
                if (gcol == grow + BHALF || grow == gcol + BHALF)
                    posv[grow] = simv;             // unique writer grid-wide
            }
            s += __shfl_xor(s, 1); s += __shfl_xor(s, 2);
            s += __shfl_xor(s, 4); s += __shfl_xor(s, 8);
            ssum[mt][r] = s;
        }
    }
    __syncthreads();
    if (wc == 0 && l15 == 0) {
        #pragma unroll
        for (int mt = 0; mt < 4; ++mt)
            #pragma unroll
            for (int r = 0; r < 4; ++r)
                pscratch[wr * 64 + mt * 16 + quad * 4 + r] = ssum[mt][r];
    }
    __syncthreads();
    if (wc == 1 && l15 == 0) {
        #pragma unroll
        for (int mt = 0; mt < 4; ++mt)
            #pragma unroll
            for (int r = 0; r < 4; ++r) {
                const int lr = wr * 64 + mt * 16 + quad * 4 + r;
                partial[blockIdx.y * NROWS + rowBase + lr] =
                    ssum[mt][r] + pscratch[lr];
            }
    }
}

// ---- Kernel 3a: per-row log-sum-exp minus positive, block partial sums ----
__global__ __launch_bounds__(256) void k_rowlse(
    const float* __restrict__ partial, const float* __restrict__ posv,
    float* __restrict__ blocksum) {
    __shared__ float red[4];
    const int tid = threadIdx.x;
    const int row = blockIdx.x * 256 + tid;
    float s = 0.f;
    #pragma unroll
    for (int p = 0; p < NCB; ++p) s += partial[p * NROWS + row];
    float v = __logf(s) - posv[row];
    #pragma unroll
    for (int m = 1; m < 64; m <<= 1) v += __shfl_xor(v, m);
    if ((tid & 63) == 0) red[tid >> 6] = v;
    __syncthreads();
    if (tid == 0)
        blocksum[blockIdx.x] = red[0] + red[1] + red[2] + red[3];
}

// ---- Kernel 3b: final 16-way sum -> loss ----------------------------------
__global__ __launch_bounds__(64) void k_final2(
    const float* __restrict__ blocksum, float* __restrict__ out) {
    const int lane = threadIdx.x;
    float v = (lane < 16) ? blocksum[lane] : 0.f;
    #pragma unroll
    for (int m = 1; m < 16; m <<= 1) v += __shfl_xor(v, m);
    if (lane == 0) out[0] = v * (1.0f / (float)NROWS);
}

extern "C" void kernel_launch(void* const* d_in, const int* in_sizes, int n_in,
                              void* d_out, int out_size, void* d_ws, size_t ws_size,
                              hipStream_t stream) {
    const float* zi = (const float*)d_in[0];
    const float* zj = (const float*)d_in[1];
    float* out = (float*)d_out;

    unsigned short* zn = (unsigned short*)d_ws;                    // 2 MB
    float* partial = (float*)((char*)d_ws + NROWS * DDIM * 2);     // 512 KB
    float* posv = partial + NCB * NROWS;                           // 16 KB
    float* blocksum = posv + NROWS;                                // 64 B

    k_normalize<<<NROWS / 4, 256, 0, stream>>>(zi, zj, zn);
    k_simlse<<<dim3(NROWS / TILE, NROWS / TILE), 256, 0, stream>>>(zn, partial, posv);
    k_rowlse<<<16, 256, 0, stream>>>(partial, posv, blocksum);
    k_final2<<<1, 64, 0, stream>>>(blocksum, out);
}

// Round 3
// 80.090 us; speedup vs baseline: 1.6044x; 1.0252x over previous
//
#include <hip/hip_runtime.h>

// NT-Xent (SimCLR) loss, B=2048, D=256, N=4096, T=0.5, eps=1e-8.
// R3: exploit sim-matrix symmetry — compute only upper-triangle 128x128
// blocks (528 vs 1024); off-diag blocks emit row-sums AND col-sums (exact
// transpose reuse: bf16 MFMA products identical either orientation).
// Note: ~42us of dur_us is the harness's 256MB d_ws poison fill (fixed).

#define NROWS 4096
#define DDIM 256
#define BHALF 2048
#define TILE 128
#define BK 64
#define LDP 72      // padded LDS row stride (shorts): 144B -> 2-way banks (free)
#define NCB (NROWS / TILE)   // 32 tile indices
#define INV_T 2.0f

typedef short bf16x8 __attribute__((ext_vector_type(8)));
typedef float f32x4 __attribute__((ext_vector_type(4)));

__device__ inline unsigned short f2bf(float f) {
    union { float f; unsigned u; } c; c.f = f;
    unsigned u = c.u + 0x7fffu + ((c.u >> 16) & 1u);  // RNE
    return (unsigned short)(u >> 16);
}

// ---- Kernel 1: row-normalize z=[z_i;z_j] into bf16 zn[4096][256] ----------
__global__ __launch_bounds__(256) void k_normalize(
    const float* __restrict__ zi, const float* __restrict__ zj,
    unsigned short* __restrict__ zn) {
    const int wave = threadIdx.x >> 6, lane = threadIdx.x & 63;
    const int row = blockIdx.x * 4 + wave;
    const float* src = (row < BHALF) ? (zi + row * DDIM)
                                     : (zj + (row - BHALF) * DDIM);
    const float4 v = ((const float4*)src)[lane];
    float ss = v.x * v.x + v.y * v.y + v.z * v.z + v.w * v.w;
    #pragma unroll
    for (int m = 1; m < 64; m <<= 1) ss += __shfl_xor(ss, m);
    const float scale = 1.0f / fmaxf(sqrtf(ss), 1e-8f);
    ushort4 o;
    o.x = f2bf(v.x * scale); o.y = f2bf(v.y * scale);
    o.z = f2bf(v.z * scale); o.w = f2bf(v.w * scale);
    ((ushort4*)(zn + row * DDIM))[lane] = o;
}

// ---- Kernel 2: upper-triangle LDS-tiled sim GEMM + exp-sum ----------------
// grid = 528 linear blocks -> (bx,by), by>=bx. Block 256 thr = 2x2 waves,
// each wave 64x64 via 4x4 mfma_f32_16x16x32_bf16.
__global__ __launch_bounds__(256) void k_simlse(
    const unsigned short* __restrict__ zn,
    float* __restrict__ partial,     // [NCB][4096], each slot 1 writer
    float* __restrict__ posv) {      // [4096]
    __shared__ unsigned short As[TILE * LDP];
    __shared__ unsigned short Bs[TILE * LDP];
    __shared__ float pscratch[TILE];   // row sums cross-wc
    __shared__ float cscratch[TILE];   // col sums cross-wr

    // triangle decode: block t -> (bx, by), by >= bx
    int t = blockIdx.x, bx = 0, rem = NCB;
    while (t >= rem) { t -= rem; ++bx; --rem; }
    const int by = bx + t;

    const int tid = threadIdx.x;
    const int wave = tid >> 6, lane = tid & 63;
    const int quad = lane >> 4, l15 = lane & 15;
    const int wr = wave >> 1, wc = wave & 1;
    const int rowBase = bx * TILE;
    const int colBase = by * TILE;

    f32x4 acc[4][4] = {};

    #pragma unroll
    for (int kb = 0; kb < DDIM / BK; ++kb) {
        __syncthreads();
        #pragma unroll
        for (int i = 0; i < 4; ++i) {
            const int flat = tid + i * 256;
            const int r = flat >> 3, c = flat & 7;
            *(bf16x8*)&As[r * LDP + c * 8] =
                *(const bf16x8*)&zn[(rowBase + r) * DDIM + kb * BK + c * 8];
            *(bf16x8*)&Bs[r * LDP + c * 8] =
                *(const bf16x8*)&zn[(colBase + r) * DDIM + kb * BK + c * 8];
        }
        __syncthreads();
        #pragma unroll
        for (int s = 0; s < 2; ++s) {
            bf16x8 af[4], bf[4];
            #pragma unroll
            for (int mt = 0; mt < 4; ++mt)
                af[mt] = *(const bf16x8*)&As[(wr * 64 + mt * 16 + l15) * LDP + s * 32 + quad * 8];
            #pragma unroll
            for (int nt = 0; nt < 4; ++nt)
                bf[nt] = *(const bf16x8*)&Bs[(wc * 64 + nt * 16 + l15) * LDP + s * 32 + quad * 8];
            #pragma unroll
            for (int mt = 0; mt < 4; ++mt)
                #pragma unroll
                for (int nt = 0; nt < 4; ++nt)
                    acc[mt][nt] = __builtin_amdgcn_mfma_f32_16x16x32_bf16(
                        af[mt], bf[nt], acc[mt][nt], 0, 0, 0);
        }
    }

    // Epilogue. C/D layout: col = lane&15, row = quad*4 + r.
    float rsum[4][4];          // [mt][r] row-sums (post-butterfly: all lanes)
    float csum[4] = {};        // [nt] per-lane col partial over 16 rows
    #pragma unroll
    for (int mt = 0; mt < 4; ++mt) {
        #pragma unroll
        for (int r = 0; r < 4; ++r) {
            const int grow = rowBase + wr * 64 + mt * 16 + quad * 4 + r;
            float s = 0.f;
            #pragma unroll
            for (int nt = 0; nt < 4; ++nt) {
                const int gcol = colBase + wc * 64 + nt * 16 + l15;
                const float simv = acc[mt][nt][r] * INV_T;
                const float e = (gcol != grow) ? __expf(simv) : 0.f;
                s += e;
                csum[nt] += e;
                if (gcol == grow + BHALF) {       // only in by==bx+16 blocks
                    posv[grow] = simv;            // sim symmetric -> both rows
                    posv[gcol] = simv;
                }
            }
            s += __shfl_xor(s, 1); s += __shfl_xor(s, 2);
            s += __shfl_xor(s, 4); s += __shfl_xor(s, 8);
            rsum[mt][r] = s;
        }
    }
    // col reduce across quads (row-index bits 4,5 of lane)
    #pragma unroll
    for (int nt = 0; nt < 4; ++nt) {
        csum[nt] += __shfl_xor(csum[nt], 16);
        csum[nt] += __shfl_xor(csum[nt], 32);
    }

    __syncthreads();
    if (wc == 0 && l15 == 0) {
        #pragma unroll
        for (int mt = 0; mt < 4; ++mt)
            #pragma unroll
            for (int r = 0; r < 4; ++r)
                pscratch[wr * 64 + mt * 16 + quad * 4 + r] = rsum[mt][r];
    }
    if (wr == 0 && quad == 0) {
        #pragma unroll
        for (int nt = 0; nt < 4; ++nt)
            cscratch[wc * 64 + nt * 16 + l15] = csum[nt];
    }
    __syncthreads();
    if (wc == 1 && l15 == 0) {    // row-sums -> partial[by][rowBase..]
        #pragma unroll
        for (int mt = 0; mt < 4; ++mt)
            #pragma unroll
            for (int r = 0; r < 4; ++r) {
                const int lr = wr * 64 + mt * 16 + quad * 4 + r;
                partial[by * NROWS + rowBase + lr] = rsum[mt][r] + pscratch[lr];
            }
    }
    if (bx != by && wr == 1 && quad == 0) {  // col-sums -> partial[bx][colBase..]
        #pragma unroll
        for (int nt = 0; nt < 4; ++nt) {
            const int lc = wc * 64 + nt * 16 + l15;
            partial[bx * NROWS + colBase + lc] = csum[nt] + cscratch[lc];
        }
    }
}

// ---- Kernel 3a: per-row log-sum-exp minus positive, block partial sums ----
__global__ __launch_bounds__(256) void k_rowlse(
    const float* __restrict__ partial, const float* __restrict__ posv,
    float* __restrict__ blocksum) {
    __shared__ float red[4];
    const int tid = threadIdx.x;
    const int row = blockIdx.x * 256 + tid;
    float s = 0.f;
    #pragma unroll
    for (int p = 0; p < NCB; ++p) s += partial[p * NROWS + row];
    float v = __logf(s) - posv[row];
    #pragma unroll
    for (int m = 1; m < 64; m <<= 1) v += __shfl_xor(v, m);
    if ((tid & 63) == 0) red[tid >> 6] = v;
    __syncthreads();
    if (tid == 0)
        blocksum[blockIdx.x] = red[0] + red[1] + red[2] + red[3];
}

// ---- Kernel 3b: final 16-way sum -> loss ----------------------------------
__global__ __launch_bounds__(64) void k_final2(
    const float* __restrict__ blocksum, float* __restrict__ out) {
    const int lane = threadIdx.x;
    float v = (lane < 16) ? blocksum[lane] : 0.f;
    #pragma unroll
    for (int m = 1; m < 16; m <<= 1) v += __shfl_xor(v, m);
    if (lane == 0) out[0] = v * (1.0f / (float)NROWS);
}

extern "C" void kernel_launch(void* const* d_in, const int* in_sizes, int n_in,
                              void* d_out, int out_size, void* d_ws, size_t ws_size,
                              hipStream_t stream) {
    const float* zi = (const float*)d_in[0];
    const float* zj = (const float*)d_in[1];
    float* out = (float*)d_out;

    unsigned short* zn = (unsigned short*)d_ws;                    // 2 MB
    float* partial = (float*)((char*)d_ws + NROWS * DDIM * 2);     // 512 KB
    float* posv = partial + NCB * NROWS;                           // 16 KB
    float* blocksum = posv + NROWS;                                // 64 B

    k_normalize<<<NROWS / 4, 256, 0, stream>>>(zi, zj, zn);
    k_simlse<<<NCB * (NCB + 1) / 2, 256, 0, stream>>>(zn, partial, posv);
    k_rowlse<<<16, 256, 0, stream>>>(partial, posv, blocksum);
    k_final2<<<1, 64, 0, stream>>>(blocksum, out);
}